// Round 3
// baseline (128.994 us; speedup 1.0000x reference)
//
#include <hip/hip_runtime.h>

#define N_IN   16384
#define N_OUT  16384
#define NE     300000

typedef unsigned int   u32;
typedef unsigned short u16;
typedef __attribute__((ext_vector_type(2))) float f32x2;
typedef __attribute__((ext_vector_type(4))) float f32x4;
typedef __attribute__((ext_vector_type(8))) short bf16x8;

// round-to-nearest-even fp32 -> bf16 bits
__device__ __forceinline__ u16 f2bf(float x) {
    union { float f; u32 u; } v; v.f = x;
    u32 r = v.u + 0x7fffu + ((v.u >> 16) & 1u);
    return (u16)(r >> 16);
}
__device__ __forceinline__ float bf2f(u16 x) {
    return __uint_as_float((u32)x << 16);
}

// ---------------------------------------------------------------------------
// Kernel A: transpose features (128, N_IN) fp32 -> ft[N_IN][128] fp32
// ---------------------------------------------------------------------------
__global__ void k_transpose(const float* __restrict__ feat, float* __restrict__ ft) {
    __shared__ float tile[32][33];
    int n0 = blockIdx.x * 32, c0 = blockIdx.y * 32;
    int tx = threadIdx.x, ty = threadIdx.y;
#pragma unroll
    for (int k = 0; k < 4; ++k)
        tile[ty + k * 8][tx] = feat[(size_t)(c0 + ty + k * 8) * N_IN + n0 + tx];
    __syncthreads();
#pragma unroll
    for (int k = 0; k < 4; ++k)
        ft[(size_t)(n0 + ty + k * 8) * 128 + c0 + tx] = tile[tx][ty + k * 8];
}

// ---------------------------------------------------------------------------
// Kernel B: segment offsets via parallel binary search over sorted idx_out
// ---------------------------------------------------------------------------
__global__ void k_segoff(const int2* __restrict__ ei, int* __restrict__ segoff) {
    int n = blockIdx.x * 256 + threadIdx.x;
    if (n > N_OUT) return;
    if (n == N_OUT) { segoff[n] = NE; return; }
    int lo = 0, hi = NE;
    while (lo < hi) { int m = (lo + hi) >> 1; if (ei[m].x < n) lo = m + 1; else hi = m; }
    segoff[n] = lo;
}

// ---------------------------------------------------------------------------
// Kernel B2: build MFMA B-fragments from W5.
// B[k][o] = W5[k>>4][((k&15)<<4)+o]  (k = j*16+i, 256 x 16)
// Bfrag[ks*512 + l*8 + e] = bf16(B[ks*32 + (l>>4)*8 + e][l&15])
// ---------------------------------------------------------------------------
__global__ void k_bfrag(const float* __restrict__ W5, u16* __restrict__ Bfrag) {
    int g = blockIdx.x * 256 + threadIdx.x;
    if (g >= 4096) return;
    int ks = g >> 9, rem = g & 511, l = rem >> 3, e = rem & 7;
    int k = ks * 32 + ((l >> 4) << 3) + e;
    int o = l & 15;
    Bfrag[g] = f2bf(W5[(k >> 4) * 256 + ((k & 15) << 4) + o]);
}

// ---------------------------------------------------------------------------
// Kernel C: per-edge MLP -> hbuf[e][16] = bf16( w_e * sin^5(...) )
// ---------------------------------------------------------------------------
__global__ void k_mlp(const float* __restrict__ pin, const float* __restrict__ pout,
                      const float* __restrict__ wts, const int2* __restrict__ ei,
                      const float* __restrict__ W0, const float* __restrict__ W1,
                      const float* __restrict__ W2, const float* __restrict__ W3,
                      const float* __restrict__ W4, u16* __restrict__ hbuf) {
    __shared__ float w0t[32];
    __shared__ float wt[4][256];   // wt[L][j*16 + i] = W(L+1)[i*16 + j]
    int tid = threadIdx.x;
    {
        int i = tid >> 4, j = tid & 15;
        if (tid < 32) w0t[(tid & 15) * 2 + (tid >> 4)] = W0[tid];
        wt[0][j * 16 + i] = W1[tid];
        wt[1][j * 16 + i] = W2[tid];
        wt[2][j * 16 + i] = W3[tid];
        wt[3][j * 16 + i] = W4[tid];
    }
    __syncthreads();
    int e = blockIdx.x * 256 + tid;
    if (e >= NE) return;

    int2 oi = ei[e];
    float2 po = ((const float2*)pout)[oi.x];
    float2 pi = ((const float2*)pin)[oi.y];
    float x = po.x - pi.x, y = po.y - pi.y;

    f32x2 h2[8];
#pragma unroll
    for (int q = 0; q < 8; ++q) {
        float ha = __sinf(x * w0t[4 * q] + y * w0t[4 * q + 1]);
        float hb = __sinf(x * w0t[4 * q + 2] + y * w0t[4 * q + 3]);
        h2[q] = (f32x2){ha, hb};
    }

#pragma unroll
    for (int L = 0; L < 4; ++L) {
        float nh[16];
#pragma unroll
        for (int j = 0; j < 16; ++j) {
            const f32x2* wr = (const f32x2*)&wt[L][j * 16];
            f32x2 acc2 = h2[0] * wr[0];
#pragma unroll
            for (int q = 1; q < 8; ++q)
                acc2 = __builtin_elementwise_fma(h2[q], wr[q], acc2);
            nh[j] = __sinf(acc2.x + acc2.y);
        }
#pragma unroll
        for (int q = 0; q < 8; ++q) h2[q] = (f32x2){nh[2 * q], nh[2 * q + 1]};
    }

    float we = wts[oi.y];
    u32 hw[8];
#pragma unroll
    for (int q = 0; q < 8; ++q)
        hw[q] = (u32)f2bf(we * h2[q].x) | ((u32)f2bf(we * h2[q].y) << 16);
    uint4* hp = (uint4*)(hbuf + (size_t)e * 16);
    hp[0] = make_uint4(hw[0], hw[1], hw[2], hw[3]);
    hp[1] = make_uint4(hw[4], hw[5], hw[6], hw[7]);
}

// ---------------------------------------------------------------------------
// Kernel D: one block (128 thr) per segment; thread t -> (b=t>>4, j=t&15).
// Accumulate S[b,i,j] = sum_e (w_e h_e[j]) ft[e.in][b*16+i]  (packed fp32),
// then store S as bf16 at S[b][n][k=j*16+i] (coalesced uint4 x2).
// ---------------------------------------------------------------------------
#define ACCP(S2, a0, a1, a2, a3, hv)                                           \
    do {                                                                       \
        S2[0] = __builtin_elementwise_fma(hv, (f32x2){a0.x, a0.y}, S2[0]);     \
        S2[1] = __builtin_elementwise_fma(hv, (f32x2){a0.z, a0.w}, S2[1]);     \
        S2[2] = __builtin_elementwise_fma(hv, (f32x2){a1.x, a1.y}, S2[2]);     \
        S2[3] = __builtin_elementwise_fma(hv, (f32x2){a1.z, a1.w}, S2[3]);     \
        S2[4] = __builtin_elementwise_fma(hv, (f32x2){a2.x, a2.y}, S2[4]);     \
        S2[5] = __builtin_elementwise_fma(hv, (f32x2){a2.z, a2.w}, S2[5]);     \
        S2[6] = __builtin_elementwise_fma(hv, (f32x2){a3.x, a3.y}, S2[6]);     \
        S2[7] = __builtin_elementwise_fma(hv, (f32x2){a3.z, a3.w}, S2[7]);     \
    } while (0)

__global__ __launch_bounds__(128) void k_gather(
        const int2* __restrict__ ei, const float* __restrict__ ft,
        const u16* __restrict__ hb, const int* __restrict__ segoff,
        u16* __restrict__ S) {
    int tid = threadIdx.x;
    int b = tid >> 4, j = tid & 15, lane = tid & 63;
    int n = blockIdx.x;
    int e0 = segoff[n], e1 = segoff[n + 1];

    f32x2 S2[8];
#pragma unroll
    for (int q = 0; q < 8; ++q) S2[q] = (f32x2){0.f, 0.f};

    for (int base = e0; base < e1; base += 64) {
        int cnt = min(64, e1 - base);
        int myi = (base + lane < e1) ? ei[base + lane].y : 0;

        // depth-2 software pipeline
        int idx = __shfl(myi, 0);
        const float4* fp = (const float4*)(ft + ((size_t)idx << 7) + (b << 4));
        float4 a0 = fp[0], a1 = fp[1], a2 = fp[2], a3 = fp[3];
        float ha = bf2f(hb[((size_t)base << 4) + j]);

        for (int i = 0; i + 1 < cnt; ++i) {
            int idx2 = __shfl(myi, i + 1);
            const float4* fp2 = (const float4*)(ft + ((size_t)idx2 << 7) + (b << 4));
            float4 c0 = fp2[0], c1 = fp2[1], c2 = fp2[2], c3 = fp2[3];
            float hc = bf2f(hb[((size_t)(base + i + 1) << 4) + j]);
            f32x2 hv = (f32x2){ha, ha};
            ACCP(S2, a0, a1, a2, a3, hv);
            a0 = c0; a1 = c1; a2 = c2; a3 = c3; ha = hc;
        }
        f32x2 hv = (f32x2){ha, ha};
        ACCP(S2, a0, a1, a2, a3, hv);
    }

    // pack 16 fp32 -> bf16, store at S[((b<<14)+n)*256 + j*16]
    u32 w[8];
#pragma unroll
    for (int q = 0; q < 8; ++q)
        w[q] = (u32)f2bf(S2[q].x) | ((u32)f2bf(S2[q].y) << 16);
    uint4* dst = (uint4*)(S + ((((size_t)(b << 14)) + n) << 8) + (j << 4));
    dst[0] = make_uint4(w[0], w[1], w[2], w[3]);
    dst[1] = make_uint4(w[4], w[5], w[6], w[7]);
}

// ---------------------------------------------------------------------------
// Kernel E: MFMA projection. Per b: out_b[n][o] = S_b (16384x256) @ B (256x16).
// Block 256 thr = 4 waves; wave handles 16 rows (n). A-frag: lane l holds
// A[row=l&15][k=(l>>4)*8+e]; B-frags preloaded; C: col=l&15, row=(l>>4)*4+reg.
// ---------------------------------------------------------------------------
__global__ __launch_bounds__(256) void k_proj(const u16* __restrict__ S,
                                              const u16* __restrict__ Bfrag,
                                              float* __restrict__ out) {
    int tid = threadIdx.x;
    int wave = tid >> 6, lane = tid & 63;
    int b = blockIdx.y;
    int n0 = (blockIdx.x * 4 + wave) << 4;

    bf16x8 bf[8];
#pragma unroll
    for (int ks = 0; ks < 8; ++ks)
        bf[ks] = *(const bf16x8*)(Bfrag + ks * 512 + lane * 8);

    f32x4 acc = {0.f, 0.f, 0.f, 0.f};
    const u16* arow = S + ((((size_t)(b << 14)) + n0 + (lane & 15)) << 8) + ((lane >> 4) << 3);
#pragma unroll
    for (int ks = 0; ks < 8; ++ks) {
        bf16x8 af = *(const bf16x8*)(arow + ks * 32);
        acc = __builtin_amdgcn_mfma_f32_16x16x32_bf16(af, bf[ks], acc, 0, 0, 0);
    }

    int o = lane & 15, r0 = (lane >> 4) << 2;
    *(float4*)(out + (((size_t)(b * 16 + o)) << 14) + n0 + r0) =
        make_float4(acc.x, acc.y, acc.z, acc.w);
}

// ---------------------------------------------------------------------------
extern "C" void kernel_launch(void* const* d_in, const int* in_sizes, int n_in,
                              void* d_out, int out_size, void* d_ws, size_t ws_size,
                              hipStream_t stream) {
    const float* pin  = (const float*)d_in[0];
    const float* pout = (const float*)d_in[1];
    const float* wts  = (const float*)d_in[2];
    const float* feat = (const float*)d_in[3];
    const int2*  ei   = (const int2*)d_in[4];
    const float* W0   = (const float*)d_in[5];
    const float* W1   = (const float*)d_in[6];
    const float* W2   = (const float*)d_in[7];
    const float* W3   = (const float*)d_in[8];
    const float* W4   = (const float*)d_in[9];
    const float* W5   = (const float*)d_in[10];
    float* out = (float*)d_out;

    u16*   S      = (u16*)d_ws;                          // 67.1 MB
    float* ft     = (float*)(S + (size_t)8 * N_OUT * 256); // 8 MB
    u16*   hbuf   = (u16*)(ft + (size_t)N_IN * 128);     // 9.6 MB
    int*   segoff = (int*)(hbuf + (size_t)NE * 16);      // 64 KB (padded)
    u16*   Bfrag  = (u16*)(segoff + 16388);              // 8 KB

    k_transpose<<<dim3(N_IN / 32, 4), dim3(32, 8), 0, stream>>>(feat, ft);
    k_segoff<<<(N_OUT + 256) / 256, 256, 0, stream>>>(ei, segoff);
    k_bfrag<<<16, 256, 0, stream>>>(W5, Bfrag);
    k_mlp<<<(NE + 255) / 256, 256, 0, stream>>>(pin, pout, wts, ei,
                                                W0, W1, W2, W3, W4, hbuf);
    k_gather<<<N_OUT, 128, 0, stream>>>(ei, ft, hbuf, segoff, S);
    k_proj<<<dim3(N_OUT / 64, 8), 256, 0, stream>>>(S, Bfrag, out);
}

// Round 4
// 91.219 us; speedup vs baseline: 1.4141x; 1.4141x over previous
//
#include <hip/hip_runtime.h>

#define N_IN   16384
#define N_OUT  16384
#define NE     300000

typedef unsigned int   u32;
typedef unsigned short u16;
typedef __attribute__((ext_vector_type(4))) float f32x4;
typedef __attribute__((ext_vector_type(8))) short bf16x8;
typedef __attribute__((ext_vector_type(2))) float f32x2;

// round-to-nearest-even fp32 -> bf16 bits
__device__ __forceinline__ u16 f2bf(float x) {
    union { float f; u32 u; } v; v.f = x;
    u32 r = v.u + 0x7fffu + ((v.u >> 16) & 1u);
    return (u16)(r >> 16);
}

// ---------------------------------------------------------------------------
// Kernel A: transpose features (128, N_IN) fp32 -> ftb[N_IN][128] bf16
// ---------------------------------------------------------------------------
__global__ void k_transpose(const float* __restrict__ feat, u16* __restrict__ ftb) {
    __shared__ float tile[32][33];
    int n0 = blockIdx.x * 32, c0 = blockIdx.y * 32;
    int tx = threadIdx.x, ty = threadIdx.y;
#pragma unroll
    for (int k = 0; k < 4; ++k)
        tile[ty + k * 8][tx] = feat[(size_t)(c0 + ty + k * 8) * N_IN + n0 + tx];
    __syncthreads();
#pragma unroll
    for (int k = 0; k < 4; ++k)
        ftb[(size_t)(n0 + ty + k * 8) * 128 + c0 + tx] = f2bf(tile[tx][ty + k * 8]);
}

// ---------------------------------------------------------------------------
// Kernel B: segment offsets via parallel binary search over sorted idx_out
// ---------------------------------------------------------------------------
__global__ void k_segoff(const int2* __restrict__ ei, int* __restrict__ segoff) {
    int n = blockIdx.x * 256 + threadIdx.x;
    if (n > N_OUT) return;
    if (n == N_OUT) { segoff[n] = NE; return; }
    int lo = 0, hi = NE;
    while (lo < hi) { int m = (lo + hi) >> 1; if (ei[m].x < n) lo = m + 1; else hi = m; }
    segoff[n] = lo;
}

// ---------------------------------------------------------------------------
// Kernel B2: build MFMA B-fragments from W5 for k_proj.
// B2[k2][o] = W5[k2>>4][((k2&15)<<4)+o]   (k2 = j*16+i, 256 x 16)
// Bfrag[ks*512 + l*8 + e] = bf16(B2[ks*32 + (l>>4)*8 + e][l&15])
// ---------------------------------------------------------------------------
__global__ void k_bfrag(const float* __restrict__ W5, u16* __restrict__ Bfrag) {
    int g = blockIdx.x * 256 + threadIdx.x;
    if (g >= 4096) return;
    int ks = g >> 9, rem = g & 511, l = rem >> 3, e = rem & 7;
    int k = ks * 32 + ((l >> 4) << 3) + e;
    int o = l & 15;
    Bfrag[g] = f2bf(W5[(k >> 4) * 256 + ((k & 15) << 4) + o]);
}

// ---------------------------------------------------------------------------
// Kernel C: per-edge MLP -> hT[j][e] = bf16( w_e * h_e[j] )   (transposed!)
// ---------------------------------------------------------------------------
__global__ void k_mlp(const float* __restrict__ pin, const float* __restrict__ pout,
                      const float* __restrict__ wts, const int2* __restrict__ ei,
                      const float* __restrict__ W0, const float* __restrict__ W1,
                      const float* __restrict__ W2, const float* __restrict__ W3,
                      const float* __restrict__ W4, u16* __restrict__ hT) {
    __shared__ float w0t[32];
    __shared__ float wt[4][256];   // wt[L][j*16 + i] = W(L+1)[i*16 + j]
    int tid = threadIdx.x;
    {
        int i = tid >> 4, j = tid & 15;
        if (tid < 32) w0t[(tid & 15) * 2 + (tid >> 4)] = W0[tid];
        wt[0][j * 16 + i] = W1[tid];
        wt[1][j * 16 + i] = W2[tid];
        wt[2][j * 16 + i] = W3[tid];
        wt[3][j * 16 + i] = W4[tid];
    }
    __syncthreads();
    int e = blockIdx.x * 256 + tid;
    if (e >= NE) return;

    int2 oi = ei[e];
    float2 po = ((const float2*)pout)[oi.x];
    float2 pi = ((const float2*)pin)[oi.y];
    float x = po.x - pi.x, y = po.y - pi.y;

    f32x2 h2[8];
#pragma unroll
    for (int q = 0; q < 8; ++q) {
        float ha = __sinf(x * w0t[4 * q] + y * w0t[4 * q + 1]);
        float hb = __sinf(x * w0t[4 * q + 2] + y * w0t[4 * q + 3]);
        h2[q] = (f32x2){ha, hb};
    }

#pragma unroll
    for (int L = 0; L < 4; ++L) {
        float nh[16];
#pragma unroll
        for (int j = 0; j < 16; ++j) {
            const f32x2* wr = (const f32x2*)&wt[L][j * 16];
            f32x2 acc2 = h2[0] * wr[0];
#pragma unroll
            for (int q = 1; q < 8; ++q)
                acc2 = __builtin_elementwise_fma(h2[q], wr[q], acc2);
            nh[j] = __sinf(acc2.x + acc2.y);
        }
#pragma unroll
        for (int q = 0; q < 8; ++q) h2[q] = (f32x2){nh[2 * q], nh[2 * q + 1]};
    }

    float we = wts[oi.y];
#pragma unroll
    for (int q = 0; q < 8; ++q) {
        hT[(size_t)(2 * q)     * NE + e] = f2bf(we * h2[q].x);
        hT[(size_t)(2 * q + 1) * NE + e] = f2bf(we * h2[q].y);
    }
}

// ---------------------------------------------------------------------------
// Kernel D: MFMA segment-gather. One block (256 thr = 4 waves) per segment.
// Per 32-edge chunk: stage gathered ft rows into LDS in A-fragment order,
// load B-frag (h) from hT with tail masking, 2 MFMA per wave (b=2w, 2w+1).
// S[b][n][k2=j*16+i] written as bf16 from C-regs.
// ---------------------------------------------------------------------------
#define STAP 528   // per-b stA stride in u16 (512 + 16 pad -> 16-bank spread)

__global__ __launch_bounds__(256) void k_gather(
        const int2* __restrict__ ei, const u16* __restrict__ ftb,
        const u16* __restrict__ hT, const int* __restrict__ segoff,
        u16* __restrict__ S) {
    __shared__ u16 stA[8 * STAP];   // 8448 B
    int tid  = threadIdx.x;
    int lane = tid & 63, wave = tid >> 6;
    int n = blockIdx.x;
    int e0 = segoff[n], e1 = segoff[n + 1];

    int b0 = wave * 2;
    f32x4 acc0 = {0.f, 0.f, 0.f, 0.f};
    f32x4 acc1 = {0.f, 0.f, 0.f, 0.f};

    // staging role: thread t stages edge sk = t>>3, channels [c8*16, c8*16+16)
    int sk = tid >> 3, c8 = tid & 7;
    // B-frag role: lane l -> col j = l&15, k-group kg = l>>4
    int j = lane & 15, kg = lane >> 4;

    bool first = true;
    for (int base = e0; base < e1; base += 32) {
        if (!first) __syncthreads();   // prior A-reads done before overwrite
        first = false;
        int cnt = e1 - base;           // valid k < min(cnt,32)

        // ---- stage A: gather ftb row for my edge, scatter to frag order ----
        int ge = base + sk;
        int idx = (ge < e1) ? ei[ge].y : 0;
        const uint4* fr = (const uint4*)(ftb + ((size_t)idx << 7) + (c8 << 4));
        uint4 fa = fr[0], fb = fr[1];
        int wbase = c8 * STAP + ((sk >> 3) * 16) * 8 + (sk & 7);
        u32 q[8] = {fa.x, fa.y, fa.z, fa.w, fb.x, fb.y, fb.z, fb.w};
#pragma unroll
        for (int m = 0; m < 8; ++m) {
            stA[wbase + (2 * m) * 8]     = (u16)(q[m] & 0xffffu);
            stA[wbase + (2 * m + 1) * 8] = (u16)(q[m] >> 16);
        }

        // ---- B-frag: masked scalar loads from hT[j][base + k] ----
        bf16x8 bq;
        const u16* hp = hT + (size_t)j * NE + base + kg * 8;
#pragma unroll
        for (int e2 = 0; e2 < 8; ++e2) {
            int k = kg * 8 + e2;
            short v = 0;
            if (k < cnt) v = *(const short*)(hp + e2);
            bq[e2] = v;
        }

        __syncthreads();   // stA ready

        // ---- A-frags + MFMA ----
        bf16x8 a0 = *(const bf16x8*)&stA[b0 * STAP + lane * 8];
        bf16x8 a1 = *(const bf16x8*)&stA[(b0 + 1) * STAP + lane * 8];
        acc0 = __builtin_amdgcn_mfma_f32_16x16x32_bf16(a0, bq, acc0, 0, 0, 0);
        acc1 = __builtin_amdgcn_mfma_f32_16x16x32_bf16(a1, bq, acc1, 0, 0, 0);
    }

    // ---- write S: C-reg (col=j=l&15, row=i=(l>>4)*4+r) -> S[b][n][j*16+i] ----
    int ig = lane >> 4;
    u32 w0 = (u32)f2bf(acc0[0]) | ((u32)f2bf(acc0[1]) << 16);
    u32 w1 = (u32)f2bf(acc0[2]) | ((u32)f2bf(acc0[3]) << 16);
    u16* d0 = S + ((((size_t)b0 << 14) + n) << 8) + j * 16 + ig * 4;
    *(uint2*)d0 = make_uint2(w0, w1);
    u32 w2 = (u32)f2bf(acc1[0]) | ((u32)f2bf(acc1[1]) << 16);
    u32 w3 = (u32)f2bf(acc1[2]) | ((u32)f2bf(acc1[3]) << 16);
    u16* d1 = S + ((((size_t)(b0 + 1) << 14) + n) << 8) + j * 16 + ig * 4;
    *(uint2*)d1 = make_uint2(w2, w3);
}

// ---------------------------------------------------------------------------
// Kernel E: MFMA projection. Per b: out_b[n][o] = S_b (16384x256) @ B2 (256x16).
// ---------------------------------------------------------------------------
__global__ __launch_bounds__(256) void k_proj(const u16* __restrict__ S,
                                              const u16* __restrict__ Bfrag,
                                              float* __restrict__ out) {
    int tid = threadIdx.x;
    int wave = tid >> 6, lane = tid & 63;
    int b = blockIdx.y;
    int n0 = (blockIdx.x * 4 + wave) << 4;

    bf16x8 bf[8];
#pragma unroll
    for (int ks = 0; ks < 8; ++ks)
        bf[ks] = *(const bf16x8*)(Bfrag + ks * 512 + lane * 8);

    f32x4 acc = {0.f, 0.f, 0.f, 0.f};
    const u16* arow = S + ((((size_t)(b << 14)) + n0 + (lane & 15)) << 8) + ((lane >> 4) << 3);
#pragma unroll
    for (int ks = 0; ks < 8; ++ks) {
        bf16x8 af = *(const bf16x8*)(arow + ks * 32);
        acc = __builtin_amdgcn_mfma_f32_16x16x32_bf16(af, bf[ks], acc, 0, 0, 0);
    }

    int o = lane & 15, r0 = (lane >> 4) << 2;
    *(float4*)(out + (((size_t)(b * 16 + o)) << 14) + n0 + r0) =
        make_float4(acc.x, acc.y, acc.z, acc.w);
}

// ---------------------------------------------------------------------------
extern "C" void kernel_launch(void* const* d_in, const int* in_sizes, int n_in,
                              void* d_out, int out_size, void* d_ws, size_t ws_size,
                              hipStream_t stream) {
    const float* pin  = (const float*)d_in[0];
    const float* pout = (const float*)d_in[1];
    const float* wts  = (const float*)d_in[2];
    const float* feat = (const float*)d_in[3];
    const int2*  ei   = (const int2*)d_in[4];
    const float* W0   = (const float*)d_in[5];
    const float* W1   = (const float*)d_in[6];
    const float* W2   = (const float*)d_in[7];
    const float* W3   = (const float*)d_in[8];
    const float* W4   = (const float*)d_in[9];
    const float* W5   = (const float*)d_in[10];
    float* out = (float*)d_out;

    u16*   S      = (u16*)d_ws;                           // 67.1 MB
    u16*   ftb    = S + (size_t)8 * N_OUT * 256;          //  4 MB
    u16*   hT     = ftb + (size_t)N_IN * 128;             //  9.6 MB
    int*   segoff = (int*)(hT + (size_t)16 * NE);         //  64 KB (pad to 16388)
    u16*   Bfrag  = (u16*)(segoff + 16388);               //  8 KB

    k_transpose<<<dim3(N_IN / 32, 4), dim3(32, 8), 0, stream>>>(feat, ftb);
    k_segoff<<<(N_OUT + 256) / 256, 256, 0, stream>>>(ei, segoff);
    k_bfrag<<<16, 256, 0, stream>>>(W5, Bfrag);
    k_mlp<<<(NE + 255) / 256, 256, 0, stream>>>(pin, pout, wts, ei,
                                                W0, W1, W2, W3, W4, hT);
    k_gather<<<N_OUT, 256, 0, stream>>>(ei, ftb, hT, segoff, S);
    k_proj<<<dim3(N_OUT / 64, 8), 256, 0, stream>>>(S, Bfrag, out);
}

// Round 5
// 68.850 us; speedup vs baseline: 1.8736x; 1.3249x over previous
//
#include <hip/hip_runtime.h>

#define N_IN   16384
#define N_OUT  16384
#define NE     300000
#define SEGS   16          // segments per gather block
#define STAP   528         // u16 stride per b in stA (512 + 16 pad)
#define SROW   264         // u16 stride per n-row in S_lds (256 + 8 pad)

typedef unsigned int   u32;
typedef unsigned short u16;
typedef __attribute__((ext_vector_type(4))) float f32x4;
typedef __attribute__((ext_vector_type(2))) float f32x2;
typedef __attribute__((ext_vector_type(8))) short bf16x8;

// round-to-nearest-even fp32 -> bf16 bits
__device__ __forceinline__ u16 f2bf(float x) {
    union { float f; u32 u; } v; v.f = x;
    u32 r = v.u + 0x7fffu + ((v.u >> 16) & 1u);
    return (u16)(r >> 16);
}

// ---------------------------------------------------------------------------
// Kernel A: transpose features (128, N_IN) fp32 -> ftb[N_IN][128] bf16
// ---------------------------------------------------------------------------
__global__ void k_transpose(const float* __restrict__ feat, u16* __restrict__ ftb) {
    __shared__ float tile[32][33];
    int n0 = blockIdx.x * 32, c0 = blockIdx.y * 32;
    int tx = threadIdx.x, ty = threadIdx.y;
#pragma unroll
    for (int k = 0; k < 4; ++k)
        tile[ty + k * 8][tx] = feat[(size_t)(c0 + ty + k * 8) * N_IN + n0 + tx];
    __syncthreads();
#pragma unroll
    for (int k = 0; k < 4; ++k)
        ftb[(size_t)(n0 + ty + k * 8) * 128 + c0 + tx] = f2bf(tile[tx][ty + k * 8]);
}

// ---------------------------------------------------------------------------
// Kernel B: segment offsets (binary search) + proj B-fragments, merged
// Bfrag[ks*512 + l*8 + e] = bf16(B2[ks*32 + (l>>4)*8 + e][l&15]),
// B2[k2][o] = W5[k2>>4][((k2&15)<<4)+o]   (k2 = j*16+i)
// ---------------------------------------------------------------------------
__global__ void k_setup(const int2* __restrict__ ei, const float* __restrict__ W5,
                        int* __restrict__ segoff, u16* __restrict__ Bfrag) {
    int g = blockIdx.x * 256 + threadIdx.x;
    if (g <= N_OUT) {
        if (g == N_OUT) segoff[g] = NE;
        else {
            int lo = 0, hi = NE;
            while (lo < hi) { int m = (lo + hi) >> 1; if (ei[m].x < g) lo = m + 1; else hi = m; }
            segoff[g] = lo;
        }
    }
    if (g < 4096) {
        int ks = g >> 9, rem = g & 511, l = rem >> 3, e = rem & 7;
        int k = ks * 32 + ((l >> 4) << 3) + e;
        int o = l & 15;
        Bfrag[g] = f2bf(W5[(k >> 4) * 256 + ((k & 15) << 4) + o]);
    }
}

// ---------------------------------------------------------------------------
// Kernel C: per-edge MLP -> hT[j][e] = bf16( w_e * h_e[j] )   (transposed)
// ---------------------------------------------------------------------------
__global__ void k_mlp(const float* __restrict__ pin, const float* __restrict__ pout,
                      const float* __restrict__ wts, const int2* __restrict__ ei,
                      const float* __restrict__ W0, const float* __restrict__ W1,
                      const float* __restrict__ W2, const float* __restrict__ W3,
                      const float* __restrict__ W4, u16* __restrict__ hT) {
    __shared__ float w0t[32];
    __shared__ float wt[4][256];   // wt[L][j*16 + i] = W(L+1)[i*16 + j]
    int tid = threadIdx.x;
    {
        int i = tid >> 4, j = tid & 15;
        if (tid < 32) w0t[(tid & 15) * 2 + (tid >> 4)] = W0[tid];
        wt[0][j * 16 + i] = W1[tid];
        wt[1][j * 16 + i] = W2[tid];
        wt[2][j * 16 + i] = W3[tid];
        wt[3][j * 16 + i] = W4[tid];
    }
    __syncthreads();
    int e = blockIdx.x * 256 + tid;
    if (e >= NE) return;

    int2 oi = ei[e];
    float2 po = ((const float2*)pout)[oi.x];
    float2 pi = ((const float2*)pin)[oi.y];
    float x = po.x - pi.x, y = po.y - pi.y;

    f32x2 h2[8];
#pragma unroll
    for (int q = 0; q < 8; ++q) {
        float ha = __sinf(x * w0t[4 * q] + y * w0t[4 * q + 1]);
        float hb = __sinf(x * w0t[4 * q + 2] + y * w0t[4 * q + 3]);
        h2[q] = (f32x2){ha, hb};
    }

#pragma unroll
    for (int L = 0; L < 4; ++L) {
        float nh[16];
#pragma unroll
        for (int j = 0; j < 16; ++j) {
            const f32x2* wr = (const f32x2*)&wt[L][j * 16];
            f32x2 acc2 = h2[0] * wr[0];
#pragma unroll
            for (int q = 1; q < 8; ++q)
                acc2 = __builtin_elementwise_fma(h2[q], wr[q], acc2);
            nh[j] = __sinf(acc2.x + acc2.y);
        }
#pragma unroll
        for (int q = 0; q < 8; ++q) h2[q] = (f32x2){nh[2 * q], nh[2 * q + 1]};
    }

    float we = wts[oi.y];
#pragma unroll
    for (int q = 0; q < 8; ++q) {
        hT[(size_t)(2 * q)     * NE + e] = f2bf(we * h2[q].x);
        hT[(size_t)(2 * q + 1) * NE + e] = f2bf(we * h2[q].y);
    }
}

// ---------------------------------------------------------------------------
// Kernel D: fused MFMA gather + projection.
// Block (256 thr = 4 waves) owns SEGS=16 consecutive segments; processes its
// contiguous edge window in pipelined 32-edge chunks. Segment boundaries
// handled by in-register B-masking; completed segments dump C-regs (bf16)
// into LDS S-tile; block epilogue projects S @ W5-frags via MFMA -> out.
// ---------------------------------------------------------------------------
#define LOAD_EI(IA, IB, BSE) do {                                         \
    int gA_ = (BSE) + 2 * pr; int gB_ = gA_ + 1;                          \
    gA_ = gA_ < NE ? gA_ : NE - 1; gB_ = gB_ < NE ? gB_ : NE - 1;         \
    IA = ei[gA_].y; IB = ei[gB_].y; } while (0)

#define LOAD_FTB(FA, FB, IA, IB) do {                                     \
    FA = ftb4[(size_t)(IA) * 16 + cg]; FB = ftb4[(size_t)(IB) * 16 + cg]; } while (0)

#define LOAD_BQ(BQ, BSE) do {                                             \
    const short* hp_ = hTs + (size_t)j * NE + (BSE) + kg * 8;             \
    BQ[0] = hp_[0]; BQ[1] = hp_[1]; BQ[2] = hp_[2]; BQ[3] = hp_[3];       \
    BQ[4] = hp_[4]; BQ[5] = hp_[5]; BQ[6] = hp_[6]; BQ[7] = hp_[7]; } while (0)

#define STAGE(FA, FB) do {                                                \
    u32 aw_[4] = {FA.x, FA.y, FA.z, FA.w};                                \
    u32 bw_[4] = {FB.x, FB.y, FB.z, FB.w};                                \
    int wb_ = bB * STAP + (pr >> 2) * 128 + 2 * (pr & 3);                 \
    _Pragma("unroll")                                                     \
    for (int m_ = 0; m_ < 8; ++m_) {                                      \
        u32 lo_ = (m_ & 1) ? (aw_[m_ >> 1] >> 16) : (aw_[m_ >> 1] & 0xffffu);      \
        u32 hi_ = (m_ & 1) ? (bw_[m_ >> 1] & 0xffff0000u) : (bw_[m_ >> 1] << 16);  \
        *(u32*)&stA[wb_ + (ibase + m_) * 8] = lo_ | hi_;                  \
    } } while (0)

#define PIECE(KLO, KHI) do {                                              \
    bf16x8 bm_;                                                           \
    _Pragma("unroll")                                                     \
    for (int e_ = 0; e_ < 8; ++e_) {                                      \
        int k_ = kg * 8 + e_;                                             \
        bm_[e_] = (k_ >= (KLO) && k_ < (KHI)) ? bqC[e_] : (short)0;       \
    }                                                                     \
    acc0 = __builtin_amdgcn_mfma_f32_16x16x32_bf16(a0, bm_, acc0, 0, 0, 0); \
    acc1 = __builtin_amdgcn_mfma_f32_16x16x32_bf16(a1, bm_, acc1, 0, 0, 0); \
} while (0)

#define DUMP() do {                                                       \
    u32 l0_ = (u32)f2bf(acc0[0]) | ((u32)f2bf(acc0[1]) << 16);            \
    u32 l1_ = (u32)f2bf(acc0[2]) | ((u32)f2bf(acc0[3]) << 16);            \
    *(uint2*)&S_lds[(b0 * 16 + s) * SROW + j * 16 + ig * 4] = make_uint2(l0_, l1_); \
    u32 l2_ = (u32)f2bf(acc1[0]) | ((u32)f2bf(acc1[1]) << 16);            \
    u32 l3_ = (u32)f2bf(acc1[2]) | ((u32)f2bf(acc1[3]) << 16);            \
    *(uint2*)&S_lds[((b0 + 1) * 16 + s) * SROW + j * 16 + ig * 4] = make_uint2(l2_, l3_); \
    acc0 = (f32x4){0.f, 0.f, 0.f, 0.f}; acc1 = (f32x4){0.f, 0.f, 0.f, 0.f}; \
} while (0)

__global__ __launch_bounds__(256, 2) void k_gather(
        const int2* __restrict__ ei, const u16* __restrict__ ftb,
        const u16* __restrict__ hT, const int* __restrict__ segoff,
        const u16* __restrict__ Bfrag, float* __restrict__ out)
{
    __shared__ __align__(16) u16 stA[8 * STAP];        //  8448 B
    __shared__ __align__(16) u16 S_lds[8 * 16 * SROW]; // 67584 B
    __shared__ int segends[SEGS + 1];

    int tid = threadIdx.x, lane = tid & 63, wave = tid >> 6;
    int s0 = blockIdx.x * SEGS;
    if (tid <= SEGS) segends[tid] = segoff[s0 + tid];
    __syncthreads();
    int e0 = segends[0], e1 = segends[SEGS];
    int nc = (e1 - e0 + 31) >> 5;

    // roles
    int pr = tid >> 4;           // edge-pair 0..15 (edges 2pr, 2pr+1 of chunk)
    int cg = tid & 15;           // channel-group: b = cg>>1, i base (cg&1)*8
    int bB = cg >> 1;
    int ibase = (cg & 1) * 8;
    int j = lane & 63 & 15, kg = lane >> 4, ig = lane >> 4;
    int b0 = wave * 2;

    const uint4* ftb4 = (const uint4*)ftb;
    const short* hTs  = (const short*)hT;

    f32x4 acc0 = {0.f, 0.f, 0.f, 0.f}, acc1 = {0.f, 0.f, 0.f, 0.f};

    if (nc == 0) {
        // no edges at all: zero this wave's S-tile rows (wave-local, no barrier)
        u32* zz = (u32*)&S_lds[(size_t)b0 * 16 * SROW];
        for (int I = lane; I < 16 * SROW; I += 64) zz[I] = 0;
    } else {
        int s = 0;
        int base = e0;
        // ---- prolog: chunk 0 fully, ei for chunk 1 ----
        int iaC, ibC; LOAD_EI(iaC, ibC, base);
        uint4 faC, fbC; LOAD_FTB(faC, fbC, iaC, ibC);
        bf16x8 bqC; LOAD_BQ(bqC, base);
        int iaN = 0, ibN = 0;
        if (nc > 1) LOAD_EI(iaN, ibN, base + 32);
        STAGE(faC, fbC);
        __syncthreads();

        for (int c = 0; c < nc; ++c) {
            // ---- prefetch: ei 2 ahead, ftb/h 1 ahead ----
            int iaN2 = 0, ibN2 = 0;
            uint4 faN = make_uint4(0, 0, 0, 0), fbN = make_uint4(0, 0, 0, 0);
            bf16x8 bqN = {0, 0, 0, 0, 0, 0, 0, 0};
            if (c + 2 < nc) LOAD_EI(iaN2, ibN2, base + 64);
            if (c + 1 < nc) { LOAD_FTB(faN, fbN, iaN, ibN); LOAD_BQ(bqN, base + 32); }

            // ---- A-frags for this chunk (read once, reused per piece) ----
            bf16x8 a0 = *(const bf16x8*)&stA[b0 * STAP + lane * 8];
            bf16x8 a1 = *(const bf16x8*)&stA[(b0 + 1) * STAP + lane * 8];

            // ---- segment pieces within this chunk ----
            int ce = base + 32;
            int k_lo = 0;
            while (s < SEGS && segends[s + 1] <= ce) {
                int k_hi = segends[s + 1] - base;
                if (k_hi > k_lo) PIECE(k_lo, k_hi);
                DUMP();
                ++s; k_lo = k_hi;
            }
            if (s < SEGS && k_lo < 32) PIECE(k_lo, 32);   // segment continues

            // ---- rotate LDS stage ----
            if (c + 1 < nc) {
                __syncthreads();
                STAGE(faN, fbN);
                __syncthreads();
            }
            faC = faN; fbC = fbN; bqC = bqN; iaN = iaN2; ibN = ibN2;
            base += 32;
        }
    }

    // ---- projection epilogue: out[b][o][16 n] = S_tile[b] @ B2 (wave-local) ----
    bf16x8 bfr[8];
#pragma unroll
    for (int ks = 0; ks < 8; ++ks)
        bfr[ks] = *(const bf16x8*)(Bfrag + ks * 512 + lane * 8);

#pragma unroll
    for (int bb = 0; bb < 2; ++bb) {
        int b = b0 + bb;
        f32x4 ap = {0.f, 0.f, 0.f, 0.f};
#pragma unroll
        for (int ks = 0; ks < 8; ++ks) {
            bf16x8 af = *(const bf16x8*)&S_lds[(b * 16 + (lane & 15)) * SROW + ks * 32 + ig * 8];
            ap = __builtin_amdgcn_mfma_f32_16x16x32_bf16(af, bfr[ks], ap, 0, 0, 0);
        }
        int o = lane & 15;
        *(float4*)(out + (((size_t)(b * 16 + o)) << 14) + s0 + ig * 4) =
            make_float4(ap[0], ap[1], ap[2], ap[3]);
    }
}

// ---------------------------------------------------------------------------
extern "C" void kernel_launch(void* const* d_in, const int* in_sizes, int n_in,
                              void* d_out, int out_size, void* d_ws, size_t ws_size,
                              hipStream_t stream) {
    const float* pin  = (const float*)d_in[0];
    const float* pout = (const float*)d_in[1];
    const float* wts  = (const float*)d_in[2];
    const float* feat = (const float*)d_in[3];
    const int2*  ei   = (const int2*)d_in[4];
    const float* W0   = (const float*)d_in[5];
    const float* W1   = (const float*)d_in[6];
    const float* W2   = (const float*)d_in[7];
    const float* W3   = (const float*)d_in[8];
    const float* W4   = (const float*)d_in[9];
    const float* W5   = (const float*)d_in[10];
    float* out = (float*)d_out;

    u16* ftb    = (u16*)d_ws;                             // 4,194,304 B
    u16* hT     = ftb + (size_t)N_IN * 128;               // 9,600,000 B + 128 B pad
    int* segoff = (int*)(hT + (size_t)16 * NE + 64);      // 65,552 B (16388 ints)
    u16* Bfrag  = (u16*)(segoff + 16388);                 // 8,192 B

    k_transpose<<<dim3(N_IN / 32, 4), dim3(32, 8), 0, stream>>>(feat, ftb);
    k_setup<<<(N_OUT + 256) / 256, 256, 0, stream>>>(ei, W5, segoff, Bfrag);
    k_mlp<<<(NE + 255) / 256, 256, 0, stream>>>(pin, pout, wts, ei,
                                                W0, W1, W2, W3, W4, hT);
    k_gather<<<N_OUT / SEGS, 256, 0, stream>>>(ei, ftb, hT, segoff, Bfrag, out);
}

// Round 6
// 66.097 us; speedup vs baseline: 1.9516x; 1.0416x over previous
//
#include <hip/hip_runtime.h>

#define N_IN   16384
#define N_OUT  16384
#define NE     300000
#define SEGS   8           // segments per gather block
#define STAP   528         // u16 stride per b in stA (512 + 16 pad)
#define SROW   264         // u16 stride per n-row in S_lds (256 + 8 pad)

typedef unsigned int   u32;
typedef unsigned short u16;
typedef __attribute__((ext_vector_type(4))) float f32x4;
typedef __attribute__((ext_vector_type(2))) float f32x2;
typedef __attribute__((ext_vector_type(8))) short bf16x8;

// round-to-nearest-even fp32 -> bf16 bits
__device__ __forceinline__ u16 f2bf(float x) {
    union { float f; u32 u; } v; v.f = x;
    u32 r = v.u + 0x7fffu + ((v.u >> 16) & 1u);
    return (u16)(r >> 16);
}

// ---------------------------------------------------------------------------
// Kernel A: transpose features (128, N_IN) fp32 -> ftb[N_IN][128] bf16
// ---------------------------------------------------------------------------
__global__ void k_transpose(const float* __restrict__ feat, u16* __restrict__ ftb) {
    __shared__ float tile[32][33];
    int n0 = blockIdx.x * 32, c0 = blockIdx.y * 32;
    int tx = threadIdx.x, ty = threadIdx.y;
#pragma unroll
    for (int k = 0; k < 4; ++k)
        tile[ty + k * 8][tx] = feat[(size_t)(c0 + ty + k * 8) * N_IN + n0 + tx];
    __syncthreads();
#pragma unroll
    for (int k = 0; k < 4; ++k)
        ftb[(size_t)(n0 + ty + k * 8) * 128 + c0 + tx] = f2bf(tile[tx][ty + k * 8]);
}

// ---------------------------------------------------------------------------
// Kernel B: segment offsets (binary search) + proj B-fragments, merged
// ---------------------------------------------------------------------------
__global__ void k_setup(const int2* __restrict__ ei, const float* __restrict__ W5,
                        int* __restrict__ segoff, u16* __restrict__ Bfrag) {
    int g = blockIdx.x * 256 + threadIdx.x;
    if (g <= N_OUT) {
        if (g == N_OUT) segoff[g] = NE;
        else {
            int lo = 0, hi = NE;
            while (lo < hi) { int m = (lo + hi) >> 1; if (ei[m].x < g) lo = m + 1; else hi = m; }
            segoff[g] = lo;
        }
    }
    if (g < 4096) {
        int ks = g >> 9, rem = g & 511, l = rem >> 3, e = rem & 7;
        int k = ks * 32 + ((l >> 4) << 3) + e;
        int o = l & 15;
        Bfrag[g] = f2bf(W5[(k >> 4) * 256 + ((k & 15) << 4) + o]);
    }
}

// ---------------------------------------------------------------------------
// Kernel C: per-edge MLP, 4 edges per thread (weights LDS-read once per 4
// edges). hT[j][e] = bf16( w_e * h_e[j] )  (transposed, coalesced stores)
// ---------------------------------------------------------------------------
__global__ __launch_bounds__(256) void k_mlp(
        const float* __restrict__ pin, const float* __restrict__ pout,
        const float* __restrict__ wts, const int2* __restrict__ ei,
        const float* __restrict__ W0, const float* __restrict__ W1,
        const float* __restrict__ W2, const float* __restrict__ W3,
        const float* __restrict__ W4, u16* __restrict__ hT) {
    __shared__ float w0t[32];
    __shared__ float wt[4][256];   // wt[L][j*16 + i] = W(L+1)[i*16 + j]
    int tid = threadIdx.x;
    {
        int i = tid >> 4, jj = tid & 15;
        if (tid < 32) w0t[(tid & 15) * 2 + (tid >> 4)] = W0[tid];
        wt[0][jj * 16 + i] = W1[tid];
        wt[1][jj * 16 + i] = W2[tid];
        wt[2][jj * 16 + i] = W3[tid];
        wt[3][jj * 16 + i] = W4[tid];
    }
    __syncthreads();
    int ebase = (blockIdx.x * 256 + tid) * 4;
    if (ebase >= NE) return;   // NE%4==0 -> all-or-nothing per thread

    const int4* eip = (const int4*)(ei + ebase);
    int4 q01 = eip[0], q23 = eip[1];
    int io_[4] = {q01.x, q01.z, q23.x, q23.z};
    int ii_[4] = {q01.y, q01.w, q23.y, q23.w};

    float x[4], y[4];
#pragma unroll
    for (int ed = 0; ed < 4; ++ed) {
        float2 po = ((const float2*)pout)[io_[ed]];
        float2 pi = ((const float2*)pin)[ii_[ed]];
        x[ed] = po.x - pi.x; y[ed] = po.y - pi.y;
    }

    f32x2 h2[4][8];
#pragma unroll
    for (int q = 0; q < 8; ++q) {
        float wa0 = w0t[4 * q],     wb0 = w0t[4 * q + 1];
        float wa1 = w0t[4 * q + 2], wb1 = w0t[4 * q + 3];
#pragma unroll
        for (int ed = 0; ed < 4; ++ed)
            h2[ed][q] = (f32x2){__sinf(x[ed] * wa0 + y[ed] * wb0),
                                __sinf(x[ed] * wa1 + y[ed] * wb1)};
    }

#pragma unroll
    for (int L = 0; L < 4; ++L) {
        f32x2 nh2[4][8];
#pragma unroll
        for (int jj = 0; jj < 16; ++jj) {
            const f32x2* wr = (const f32x2*)&wt[L][jj * 16];
            f32x2 wv[8];
#pragma unroll
            for (int q = 0; q < 8; ++q) wv[q] = wr[q];
#pragma unroll
            for (int ed = 0; ed < 4; ++ed) {
                f32x2 acc = h2[ed][0] * wv[0];
#pragma unroll
                for (int q = 1; q < 8; ++q)
                    acc = __builtin_elementwise_fma(h2[ed][q], wv[q], acc);
                float hv = __sinf(acc.x + acc.y);
                if (jj & 1) nh2[ed][jj >> 1].y = hv; else nh2[ed][jj >> 1].x = hv;
            }
        }
#pragma unroll
        for (int ed = 0; ed < 4; ++ed)
#pragma unroll
            for (int q = 0; q < 8; ++q) h2[ed][q] = nh2[ed][q];
    }

    float we[4];
#pragma unroll
    for (int ed = 0; ed < 4; ++ed) we[ed] = wts[ii_[ed]];
#pragma unroll
    for (int jj = 0; jj < 16; ++jj) {
        int q = jj >> 1;
        float v0 = (jj & 1) ? h2[0][q].y : h2[0][q].x;
        float v1 = (jj & 1) ? h2[1][q].y : h2[1][q].x;
        float v2 = (jj & 1) ? h2[2][q].y : h2[2][q].x;
        float v3 = (jj & 1) ? h2[3][q].y : h2[3][q].x;
        u32 lo = (u32)f2bf(we[0] * v0) | ((u32)f2bf(we[1] * v1) << 16);
        u32 hi = (u32)f2bf(we[2] * v2) | ((u32)f2bf(we[3] * v3) << 16);
        *(uint2*)(hT + (size_t)jj * NE + ebase) = make_uint2(lo, hi);
    }
}

// ---------------------------------------------------------------------------
// Kernel D: fused MFMA gather + projection. SEGS=8 segments per block
// (256 thr = 4 waves). Chunks aligned to absolute 32-edge grid; depth-2
// prefetch on ei/ftb/h; double-buffered stA -> one barrier per chunk.
// ---------------------------------------------------------------------------
#define EIv(IA, IB, BSE) do {                                             \
    int g_ = (BSE) + 2 * pr; g_ = g_ <= NE - 2 ? g_ : NE - 2;             \
    int4 q_ = *(const int4*)(ei + g_); IA = q_.y; IB = q_.w; } while (0)

#define FTBv(FA, FB, IA, IB) do {                                         \
    FA = ftb4[(size_t)(u32)(IA) * 16 + cg];                               \
    FB = ftb4[(size_t)(u32)(IB) * 16 + cg]; } while (0)

#define BQv(BQ, BSE) do {                                                 \
    int bb_ = (BSE); bb_ = bb_ <= NE - 32 ? bb_ : NE - 32;                \
    BQ = *(const bf16x8*)(hT + (size_t)j * NE + bb_ + kg * 8); } while (0)

#define STAGEv(BUF, FA, FB) do {                                          \
    u32 aw_[4] = {FA.x, FA.y, FA.z, FA.w};                                \
    u32 bw_[4] = {FB.x, FB.y, FB.z, FB.w};                                \
    int wb_ = bB * STAP + (pr >> 2) * 128 + 2 * (pr & 3);                 \
    _Pragma("unroll")                                                     \
    for (int m_ = 0; m_ < 8; ++m_) {                                      \
        u32 lo_ = (m_ & 1) ? (aw_[m_ >> 1] >> 16) : (aw_[m_ >> 1] & 0xffffu);      \
        u32 hi_ = (m_ & 1) ? (bw_[m_ >> 1] & 0xffff0000u) : (bw_[m_ >> 1] << 16);  \
        *(u32*)&stA[BUF][wb_ + (ibase + m_) * 8] = lo_ | hi_;             \
    } } while (0)

#define PIECE(KLO, KHI, BQ) do {                                          \
    bf16x8 bm_;                                                           \
    if ((KLO) == 0 && (KHI) == 32) { bm_ = BQ; }                          \
    else {                                                                \
        _Pragma("unroll")                                                 \
        for (int e_ = 0; e_ < 8; ++e_) {                                  \
            int k_ = kg * 8 + e_;                                         \
            bm_[e_] = (k_ >= (KLO) && k_ < (KHI)) ? BQ[e_] : (short)0;    \
        }                                                                 \
    }                                                                     \
    acc0 = __builtin_amdgcn_mfma_f32_16x16x32_bf16(a0, bm_, acc0, 0, 0, 0); \
    acc1 = __builtin_amdgcn_mfma_f32_16x16x32_bf16(a1, bm_, acc1, 0, 0, 0); \
} while (0)

#define DUMP() do {                                                       \
    u32 l0_ = (u32)f2bf(acc0[0]) | ((u32)f2bf(acc0[1]) << 16);            \
    u32 l1_ = (u32)f2bf(acc0[2]) | ((u32)f2bf(acc0[3]) << 16);            \
    *(uint2*)&S_lds[(b0 * SEGS + s) * SROW + j * 16 + kg * 4] = make_uint2(l0_, l1_); \
    u32 l2_ = (u32)f2bf(acc1[0]) | ((u32)f2bf(acc1[1]) << 16);            \
    u32 l3_ = (u32)f2bf(acc1[2]) | ((u32)f2bf(acc1[3]) << 16);            \
    *(uint2*)&S_lds[((b0 + 1) * SEGS + s) * SROW + j * 16 + kg * 4] = make_uint2(l2_, l3_); \
    acc0 = (f32x4){0.f, 0.f, 0.f, 0.f}; acc1 = (f32x4){0.f, 0.f, 0.f, 0.f}; \
} while (0)

__global__ __launch_bounds__(256, 3) void k_gather(
        const int2* __restrict__ ei, const u16* __restrict__ ftb,
        const u16* __restrict__ hT, const int* __restrict__ segoff,
        const u16* __restrict__ Bfrag, float* __restrict__ out)
{
    __shared__ __align__(16) u16 stA[2][8 * STAP];      // 16,896 B
    __shared__ __align__(16) u16 S_lds[8 * SEGS * SROW];// 33,792 B
    __shared__ int segends[SEGS + 1];

    int tid = threadIdx.x, lane = tid & 63, wave = tid >> 6;
    int s0 = blockIdx.x * SEGS;
    if (tid <= SEGS) segends[tid] = segoff[s0 + tid];
    __syncthreads();
    int e0 = segends[0], e1 = segends[SEGS];
    int base0 = e0 & ~31;                 // absolute-aligned chunk grid
    int nc = (e1 - base0 + 31) >> 5;

    // roles
    int pr = tid >> 4;                    // edge-pair 0..15
    int cg = tid & 15;                    // 8-channel group
    int bB = cg >> 1, ibase = (cg & 1) * 8;
    int j = lane & 15, kg = lane >> 4;
    int b0 = wave * 2;

    const uint4* ftb4 = (const uint4*)ftb;
    f32x4 acc0 = {0.f, 0.f, 0.f, 0.f}, acc1 = {0.f, 0.f, 0.f, 0.f};

    if (nc > 0) {
        // ---- prolog: chunk0 loaded+staged; chunk1 loaded; ei for chunk2 ----
        int iaS, ibS, eiA, eiB;
        uint4 faS, fbS;
        bf16x8 bqC, bqN;
        EIv(eiA, eiB, base0);
        FTBv(faS, fbS, eiA, eiB);
        BQv(bqC, base0);
        EIv(eiA, eiB, base0 + 32);
        STAGEv(0, faS, fbS);
        FTBv(faS, fbS, eiA, eiB);          // chunk1 data (to stage in iter 0)
        BQv(bqN, base0 + 32);
        EIv(eiA, eiB, base0 + 64);         // ei for chunk2
        __syncthreads();

        int s = 0;
        for (int c = 0; c < nc; ++c) {
            int base = base0 + 32 * c;
            int buf = c & 1;

            // A-frags for chunk c
            bf16x8 a0 = *(const bf16x8*)&stA[buf][b0 * STAP + lane * 8];
            bf16x8 a1 = *(const bf16x8*)&stA[buf][(b0 + 1) * STAP + lane * 8];

            // stage chunk c+1 (data already in regs -> no HBM stall)
            STAGEv(buf ^ 1, faS, fbS);

            // prefetch chunk c+2 data, ei for chunk c+3 (clamped, branch-free)
            uint4 faL, fbL; bf16x8 bqL; int eiA2, eiB2;
            FTBv(faL, fbL, eiA, eiB);
            BQv(bqL, base + 64);
            EIv(eiA2, eiB2, base + 96);

            // segment pieces within chunk c
            int ce = base + 32;
            int k_lo = (c == 0) ? (e0 - base0) : 0;
            while (s < SEGS && segends[s + 1] <= ce) {
                int k_hi = segends[s + 1] - base;
                if (k_hi > k_lo) PIECE(k_lo, k_hi, bqC);
                DUMP();
                ++s; k_lo = k_hi;
            }
            if (s < SEGS && k_lo < 32) PIECE(k_lo, 32, bqC);

            if (c + 1 < nc) __syncthreads();

            // rotate pipeline regs
            faS = faL; fbS = fbL;
            bqC = bqN; bqN = bqL;
            eiA = eiA2; eiB = eiB2;
        }
    } else {
        // empty window: zero this wave's S rows (wave-local)
        u32* zz = (u32*)&S_lds[b0 * SEGS * SROW];
        for (int I = lane; I < SEGS * SROW; I += 64) zz[I] = 0;
    }

    // ---- projection epilogue (wave-local: reads only own b rows) ----
    bf16x8 bfr[8];
#pragma unroll
    for (int ks = 0; ks < 8; ++ks)
        bfr[ks] = *(const bf16x8*)(Bfrag + ks * 512 + lane * 8);

#pragma unroll
    for (int bb = 0; bb < 2; ++bb) {
        int b = b0 + bb;
        f32x4 ap = {0.f, 0.f, 0.f, 0.f};
#pragma unroll
        for (int ks = 0; ks < 8; ++ks) {
            bf16x8 af = *(const bf16x8*)
                &S_lds[(b * SEGS + (lane & 7)) * SROW + ks * 32 + kg * 8];
            ap = __builtin_amdgcn_mfma_f32_16x16x32_bf16(af, bfr[ks], ap, 0, 0, 0);
        }
        int o = lane & 15;
        if (kg < 2)   // rows 0..7 valid (SEGS=8); rows 8..15 are duplicates
            *(float4*)(out + (((size_t)(b * 16 + o)) << 14) + s0 + kg * 4) =
                make_float4(ap[0], ap[1], ap[2], ap[3]);
    }
}

// ---------------------------------------------------------------------------
extern "C" void kernel_launch(void* const* d_in, const int* in_sizes, int n_in,
                              void* d_out, int out_size, void* d_ws, size_t ws_size,
                              hipStream_t stream) {
    const float* pin  = (const float*)d_in[0];
    const float* pout = (const float*)d_in[1];
    const float* wts  = (const float*)d_in[2];
    const float* feat = (const float*)d_in[3];
    const int2*  ei   = (const int2*)d_in[4];
    const float* W0   = (const float*)d_in[5];
    const float* W1   = (const float*)d_in[6];
    const float* W2   = (const float*)d_in[7];
    const float* W3   = (const float*)d_in[8];
    const float* W4   = (const float*)d_in[9];
    const float* W5   = (const float*)d_in[10];
    float* out = (float*)d_out;

    u16* ftb    = (u16*)d_ws;                             // 4,194,304 B
    u16* hT     = ftb + (size_t)N_IN * 128;               // 9,600,000 B + pad
    int* segoff = (int*)(hT + (size_t)16 * NE + 64);      // 65,552 B
    u16* Bfrag  = (u16*)(segoff + 16388);                 // 8,192 B

    k_transpose<<<dim3(N_IN / 32, 4), dim3(32, 8), 0, stream>>>(feat, ftb);
    k_setup<<<(N_OUT + 256) / 256, 256, 0, stream>>>(ei, W5, segoff, Bfrag);
    k_mlp<<<(NE + 1023) / 1024, 256, 0, stream>>>(pin, pout, wts, ei,
                                                  W0, W1, W2, W3, W4, hT);
    k_gather<<<N_OUT / SEGS, 256, 0, stream>>>(ei, ftb, hT, segoff, Bfrag, out);
}